// Round 3
// baseline (96.921 us; speedup 1.0000x reference)
//
#include <hip/hip_runtime.h>

// ---------------------------------------------------------------------------
// KAN conv as 3x3 conv, Cin=288 (9 spline/silu feats x 32 ch), Cout=64:
//   g[b][h][w][j][c]  padded 34x34 feature tensor, bf16 (border t=0 cells
//                     materialized: basis(0) != 0)
//   Wb[o][pos][j][c]  folded weights bf16
//   out = conv(g, Wb) + bias
// 3 kernels:
//   kan_feat   : build g + Wb
//   kan_conv   : grid (128 m-tiles x 9 positions), 4 waves; wave = O16 x M64
//                via mfma_f32_16x16x32_bf16 (first op = Wb -> D-row = o);
//                direct fp32 partial stores to part[pos][o][l]  (no atomics)
//   kan_reduce : out[b][o][pix] = sum_pos part[pos][o][l] + bias[o], float4
// Workspace: g 5,326,848 B + Wb 331,776 B + part 18,874,368 B  (~24 MB)
// ---------------------------------------------------------------------------

typedef __attribute__((ext_vector_type(8))) short v8s;
typedef __attribute__((ext_vector_type(4))) float v4f;
typedef unsigned short ushort_t;

#define G_ELEMS   (8u * 34u * 34u * 288u)   // 2,663,424 bf16
#define WB_ELEMS  (64u * 2592u)             // 165,888 bf16
#define N_FEAT    (8 * 34 * 34 * 32)        // 295,936 feature threads
#define N_TOTAL   (N_FEAT + 64 * 2592)      // + 165,888 Wb threads
#define PART_STRIDE 524288u                 // 64 * 8192 floats per position

__device__ __forceinline__ unsigned short f2bf(float v) {
  union { float f; unsigned int u; } w; w.f = v;
  unsigned int r = w.u + 0x7FFFu + ((w.u >> 16) & 1u);   // RNE
  return (unsigned short)(r >> 16);
}

// ---------------------------------------------------------------------------
// Kernel 1: build g (padded features) and Wb (folded bf16 weights).
// ---------------------------------------------------------------------------
__global__ __launch_bounds__(256) void kan_feat(const float* __restrict__ x,
                                                const float* __restrict__ coef,
                                                const float* __restrict__ sb,
                                                const float* __restrict__ ssp,
                                                ushort_t* __restrict__ g,
                                                ushort_t* __restrict__ Wb) {
  int tid = blockIdx.x * 256 + threadIdx.x;
  if (tid < N_FEAT) {
    int c = tid & 31;
    int cell = tid >> 5;              // (b*34 + h)*34 + w
    int w = cell % 34;
    int hb = cell / 34;
    int h = hb % 34;
    int b = hb / 34;

    bool inb = (h >= 1) && (h <= 32) && (w >= 1) && (w <= 32);
    float t = 0.0f;
    if (inb) t = x[((b * 32 + c) * 32 + (h - 1)) * 32 + (w - 1)];

    unsigned short f0 = f2bf(t / (1.0f + __expf(-t)));   // silu
    // cubic uniform B-spline, knots -2.2 + 0.4*i
    float u  = (t + 2.2f) * 2.5f;
    float fi = floorf(u);
    int   i  = (int)fi;
    float s  = u - fi;
    float s2 = s * s, s3 = s2 * s;
    float om = 1.0f - s;
    float w0 = om * om * om * (1.0f / 6.0f);
    float w1 = (4.0f - 6.0f * s2 + 3.0f * s3) * (1.0f / 6.0f);
    float w2 = (1.0f + 3.0f * s + 3.0f * s2 - 3.0f * s3) * (1.0f / 6.0f);
    float w3 = s3 * (1.0f / 6.0f);

    ushort_t* dst = g + (size_t)cell * 288 + c;
    dst[0] = f0;
#pragma unroll
    for (int jj = 0; jj < 8; ++jj) {
      int d = jj - i + 3;
      float bv = (d == 0) ? w0 : (d == 1) ? w1 : (d == 2) ? w2 : (d == 3) ? w3 : 0.0f;
      dst[(jj + 1) * 32] = f2bf(bv);
    }
    return;
  }
  int i2 = tid - N_FEAT;              // Wb flat: o*2592 + pos*288 + j*32 + c
  if (i2 >= (int)WB_ELEMS) return;
  int o = i2 / 2592;
  int r = i2 - o * 2592;
  int pos = r / 288;
  int rj = r - pos * 288;
  int j = rj >> 5;
  int c = rj & 31;
  int sidx = (o * 32 + c) * 9 + pos;
  float val = (j == 0) ? sb[sidx] : ssp[sidx] * coef[sidx * 8 + (j - 1)];
  Wb[i2] = f2bf(val);
}

// ---------------------------------------------------------------------------
// Kernel 2: conv partials.  grid (128, 9): x = m-tile (64 pixels), y = pos.
// 4 waves; wave covers O16 (obase = wave*16) x M64.  Fully static K-chunk:
// pos fixed -> (di,dj) fixed, 9 unrolled ksteps of 32.
// MFMA first operand  = Wb rows  (lane&15 = o,     k = quad*8+j)
//      second operand = g rows   (lane&15 = pixel, k = quad*8+j)
//      D: row(quad*4+reg) = o, col(lane&15) = pixel
// Store partial at part[pos][o][l]  (16 scalar stores/lane, 4x64B segs each).
// ---------------------------------------------------------------------------
__global__ __launch_bounds__(256) void kan_conv(const ushort_t* __restrict__ g,
                                                const ushort_t* __restrict__ Wb,
                                                float* __restrict__ part) {
  const int lane = threadIdx.x & 63;
  const int wave = threadIdx.x >> 6;
  const int row  = lane & 15;
  const int quad = lane >> 4;
  const int mbase = blockIdx.x * 64;       // 64 pixels: one b, 2 oh rows
  const int pos   = blockIdx.y;
  const int di = pos / 3, dj = pos - di * 3;

  const int b   = mbase >> 10;
  const int oh0 = (mbase & 1023) >> 5;
  const int obase = wave * 16;

  const ushort_t* wp = Wb + (size_t)(obase + row) * 2592 + pos * 288 + quad * 8;

  const ushort_t* gp[4];
#pragma unroll
  for (int mseg = 0; mseg < 4; ++mseg) {
    int ohs = oh0 + (mseg >> 1) + di;          // padded h
    int ows = (mseg & 1) * 16 + row + dj;      // padded w
    gp[mseg] = g + (size_t)((b * 34 + ohs) * 34 + ows) * 288 + quad * 8;
  }

  v4f acc0 = {0.f, 0.f, 0.f, 0.f};
  v4f acc1 = acc0, acc2 = acc0, acc3 = acc0;

#pragma unroll
  for (int kk = 0; kk < 9; ++kk) {
    v8s wf = *(const v8s*)(wp + kk * 32);
    v8s g0 = *(const v8s*)(gp[0] + kk * 32);
    v8s g1 = *(const v8s*)(gp[1] + kk * 32);
    v8s g2 = *(const v8s*)(gp[2] + kk * 32);
    v8s g3 = *(const v8s*)(gp[3] + kk * 32);
    acc0 = __builtin_amdgcn_mfma_f32_16x16x32_bf16(wf, g0, acc0, 0, 0, 0);
    acc1 = __builtin_amdgcn_mfma_f32_16x16x32_bf16(wf, g1, acc1, 0, 0, 0);
    acc2 = __builtin_amdgcn_mfma_f32_16x16x32_bf16(wf, g2, acc2, 0, 0, 0);
    acc3 = __builtin_amdgcn_mfma_f32_16x16x32_bf16(wf, g3, acc3, 0, 0, 0);
  }

  float* pb = part + (size_t)pos * PART_STRIDE
            + (size_t)(obase + quad * 4) * 8192 + mbase + row;
#pragma unroll
  for (int r = 0; r < 4; ++r) {
    float* pr = pb + (size_t)r * 8192;
    pr[0]  = acc0[r];
    pr[16] = acc1[r];
    pr[32] = acc2[r];
    pr[48] = acc3[r];
  }
}

// ---------------------------------------------------------------------------
// Kernel 3: out[b][o][pix] = sum_pos part[pos][o][l] + bias[o].
// 512 blocks x 256 thr, float4 per thread; reads and writes stride-1.
// ---------------------------------------------------------------------------
__global__ __launch_bounds__(256) void kan_reduce(const float* __restrict__ part,
                                                  const float* __restrict__ bias,
                                                  float* __restrict__ out) {
  int tid = blockIdx.x * 256 + threadIdx.x;   // 131072 threads
  int flat = tid * 4;                         // o*8192 + l
  int o = flat >> 13;
  int l = flat & 8191;
  int b = l >> 10;
  int pix = l & 1023;

  float4 s = *(const float4*)(part + flat);
#pragma unroll
  for (int ks = 1; ks < 9; ++ks) {
    float4 p = *(const float4*)(part + (size_t)ks * PART_STRIDE + flat);
    s.x += p.x; s.y += p.y; s.z += p.z; s.w += p.w;
  }
  float bv = bias[o];
  s.x += bv; s.y += bv; s.z += bv; s.w += bv;
  *(float4*)(out + (size_t)(b * 64 + o) * 1024 + pix) = s;
}

// ---------------------------------------------------------------------------
extern "C" void kernel_launch(void* const* d_in, const int* in_sizes, int n_in,
                              void* d_out, int out_size, void* d_ws, size_t ws_size,
                              hipStream_t stream) {
  const float* x    = (const float*)d_in[0];
  const float* coef = (const float*)d_in[1];
  const float* sb   = (const float*)d_in[2];
  const float* ssp  = (const float*)d_in[3];
  const float* bias = (const float*)d_in[4];
  float* out = (float*)d_out;

  ushort_t* g    = (ushort_t*)d_ws;            // 5,326,848 B
  ushort_t* Wb   = g + G_ELEMS;                // +331,776 B
  float*    part = (float*)(Wb + WB_ELEMS);    // +18,874,368 B (16B aligned)

  hipLaunchKernelGGL(kan_feat, dim3((N_TOTAL + 255) / 256), dim3(256), 0, stream,
                     x, coef, sb, ssp, g, Wb);
  hipLaunchKernelGGL(kan_conv, dim3(128, 9), dim3(256), 0, stream, g, Wb, part);
  hipLaunchKernelGGL(kan_reduce, dim3(512), dim3(256), 0, stream, part, bias, out);
}

// Round 4
// 95.608 us; speedup vs baseline: 1.0137x; 1.0137x over previous
//
#include <hip/hip_runtime.h>

// ---------------------------------------------------------------------------
// KAN conv as 3x3 conv, Cin=288 (9 spline/silu feats x 32 ch), Cout=64:
//   g[b][h][w][j][c]  padded 34x34 feature tensor, bf16 (border t=0 cells
//                     materialized: basis(0) != 0)
//   Wb[o][pos][j][c]  folded weights bf16
//   out = conv(g, Wb) + bias
// Round-4 structure (fixing R3's 40MB partial round-trip, keeping occupancy):
//   kan_feat   : build g + Wb (unchanged)
//   kan_conv   : grid (512 m-tiles of M16  x  2 K-halves), 4 waves/block,
//                wave = O16 x M16, __launch_bounds__(256,4) -> 4 waves/SIMD.
//                K-half 0 = pos 0..3, K-half 1 = pos 4..8 (static unroll).
//                Partials: part[y][o][l], 2 x 2 MB fp32, no atomics.
//   kan_reduce : out = part0 + part1 + bias, float4 (6 MB, L2-hot)
// Workspace: g 5,326,848 + Wb 331,776 + part 4,194,304  (~9.7 MB)
// ---------------------------------------------------------------------------

typedef __attribute__((ext_vector_type(8))) short v8s;
typedef __attribute__((ext_vector_type(4))) float v4f;
typedef unsigned short ushort_t;

#define G_ELEMS   (8u * 34u * 34u * 288u)   // 2,663,424 bf16
#define WB_ELEMS  (64u * 2592u)             // 165,888 bf16
#define N_FEAT    (8 * 34 * 34 * 32)        // 295,936 feature threads
#define N_TOTAL   (N_FEAT + 64 * 2592)      // + 165,888 Wb threads
#define PART_STRIDE 524288u                 // 64 * 8192 floats per K-half

__device__ __forceinline__ unsigned short f2bf(float v) {
  union { float f; unsigned int u; } w; w.f = v;
  unsigned int r = w.u + 0x7FFFu + ((w.u >> 16) & 1u);   // RNE
  return (unsigned short)(r >> 16);
}

// ---------------------------------------------------------------------------
// Kernel 1: build g (padded features) and Wb (folded bf16 weights).
// ---------------------------------------------------------------------------
__global__ __launch_bounds__(256) void kan_feat(const float* __restrict__ x,
                                                const float* __restrict__ coef,
                                                const float* __restrict__ sb,
                                                const float* __restrict__ ssp,
                                                ushort_t* __restrict__ g,
                                                ushort_t* __restrict__ Wb) {
  int tid = blockIdx.x * 256 + threadIdx.x;
  if (tid < N_FEAT) {
    int c = tid & 31;
    int cell = tid >> 5;              // (b*34 + h)*34 + w
    int w = cell % 34;
    int hb = cell / 34;
    int h = hb % 34;
    int b = hb / 34;

    bool inb = (h >= 1) && (h <= 32) && (w >= 1) && (w <= 32);
    float t = 0.0f;
    if (inb) t = x[((b * 32 + c) * 32 + (h - 1)) * 32 + (w - 1)];

    unsigned short f0 = f2bf(t / (1.0f + __expf(-t)));   // silu
    // cubic uniform B-spline, knots -2.2 + 0.4*i
    float u  = (t + 2.2f) * 2.5f;
    float fi = floorf(u);
    int   i  = (int)fi;
    float s  = u - fi;
    float s2 = s * s, s3 = s2 * s;
    float om = 1.0f - s;
    float w0 = om * om * om * (1.0f / 6.0f);
    float w1 = (4.0f - 6.0f * s2 + 3.0f * s3) * (1.0f / 6.0f);
    float w2 = (1.0f + 3.0f * s + 3.0f * s2 - 3.0f * s3) * (1.0f / 6.0f);
    float w3 = s3 * (1.0f / 6.0f);

    ushort_t* dst = g + (size_t)cell * 288 + c;
    dst[0] = f0;
#pragma unroll
    for (int jj = 0; jj < 8; ++jj) {
      int d = jj - i + 3;
      float bv = (d == 0) ? w0 : (d == 1) ? w1 : (d == 2) ? w2 : (d == 3) ? w3 : 0.0f;
      dst[(jj + 1) * 32] = f2bf(bv);
    }
    return;
  }
  int i2 = tid - N_FEAT;              // Wb flat: o*2592 + pos*288 + j*32 + c
  if (i2 >= (int)WB_ELEMS) return;
  int o = i2 / 2592;
  int r = i2 - o * 2592;
  int pos = r / 288;
  int rj = r - pos * 288;
  int j = rj >> 5;
  int c = rj & 31;
  int sidx = (o * 32 + c) * 9 + pos;
  float val = (j == 0) ? sb[sidx] : ssp[sidx] * coef[sidx * 8 + (j - 1)];
  Wb[i2] = f2bf(val);
}

// ---------------------------------------------------------------------------
// Kernel 2: conv partials.  grid (512, 2): x = M16 pixel tile, y = K-half.
// Block = 4 waves; wave = O16 (obase = wave*16) x M16 (all 16 pixels).
// MFMA: first operand = Wb row (lane&15 = o), second = g row (lane&15 = pix),
//       D: row(quad*4+reg) = o, col(lane&15) = pixel.
// K-half 0: pos 0..3 (36 ksteps); K-half 1: pos 4..8 (45 ksteps).
// All g/Wb offsets static from 3 per-di base pointers -> immediate folding.
// ---------------------------------------------------------------------------
__global__ __launch_bounds__(256, 4) void kan_conv(const ushort_t* __restrict__ g,
                                                   const ushort_t* __restrict__ Wb,
                                                   float* __restrict__ part) {
  const int lane = threadIdx.x & 63;
  const int wave = threadIdx.x >> 6;
  const int row  = lane & 15;
  const int quad = lane >> 4;
  const int mbase = blockIdx.x * 16;       // 16 pixels in one oh row
  const int b   = mbase >> 10;
  const int oh  = (mbase & 1023) >> 5;
  const int ow0 = mbase & 31;              // 0 or 16
  const int obase = wave * 16;

  const ushort_t* wp = Wb + (size_t)(obase + row) * 2592 + quad * 8;

  // one g base pointer per di (padded h = oh + di); dj/kk are static offsets
  const ushort_t* gb0 = g + (size_t)((b * 34 + oh)     * 34 + ow0 + row) * 288 + quad * 8;
  const ushort_t* gb1 = gb0 + 34 * 288;
  const ushort_t* gb2 = gb1 + 34 * 288;

  v4f acc = {0.f, 0.f, 0.f, 0.f};

#define KSTEP(GB, DJ, POS, KK)                                                 \
  do {                                                                         \
    v8s wf = *(const v8s*)(wp + ((POS) * 288 + (KK) * 32));                    \
    v8s gf = *(const v8s*)((GB) + ((DJ) * 288 + (KK) * 32));                   \
    acc = __builtin_amdgcn_mfma_f32_16x16x32_bf16(wf, gf, acc, 0, 0, 0);       \
  } while (0)

#define POS_BLOCK(GB, DJ, POS)                                                 \
  do {                                                                         \
    KSTEP(GB, DJ, POS, 0); KSTEP(GB, DJ, POS, 1); KSTEP(GB, DJ, POS, 2);       \
    KSTEP(GB, DJ, POS, 3); KSTEP(GB, DJ, POS, 4); KSTEP(GB, DJ, POS, 5);       \
    KSTEP(GB, DJ, POS, 6); KSTEP(GB, DJ, POS, 7); KSTEP(GB, DJ, POS, 8);       \
  } while (0)

  if (blockIdx.y == 0) {
    POS_BLOCK(gb0, 0, 0);
    POS_BLOCK(gb0, 1, 1);
    POS_BLOCK(gb0, 2, 2);
    POS_BLOCK(gb1, 0, 3);
  } else {
    POS_BLOCK(gb1, 1, 4);
    POS_BLOCK(gb1, 2, 5);
    POS_BLOCK(gb2, 0, 6);
    POS_BLOCK(gb2, 1, 7);
    POS_BLOCK(gb2, 2, 8);
  }
#undef POS_BLOCK
#undef KSTEP

  float* pb = part + (size_t)blockIdx.y * PART_STRIDE
            + (size_t)(obase + quad * 4) * 8192 + mbase + row;
#pragma unroll
  for (int r = 0; r < 4; ++r) {
    pb[(size_t)r * 8192] = acc[r];
  }
}

// ---------------------------------------------------------------------------
// Kernel 3: out[b][o][pix] = part0[o][l] + part1[o][l] + bias[o].
// 512 blocks x 256 thr, float4; reads and writes stride-1, L2-hot.
// ---------------------------------------------------------------------------
__global__ __launch_bounds__(256) void kan_reduce(const float* __restrict__ part,
                                                  const float* __restrict__ bias,
                                                  float* __restrict__ out) {
  int tid = blockIdx.x * 256 + threadIdx.x;   // 131072 threads
  int flat = tid * 4;                         // o*8192 + l
  int o = flat >> 13;
  int l = flat & 8191;
  int b = l >> 10;
  int pix = l & 1023;

  float4 s0 = *(const float4*)(part + flat);
  float4 s1 = *(const float4*)(part + PART_STRIDE + flat);
  float bv = bias[o];
  float4 s = make_float4(s0.x + s1.x + bv, s0.y + s1.y + bv,
                         s0.z + s1.z + bv, s0.w + s1.w + bv);
  *(float4*)(out + (size_t)(b * 64 + o) * 1024 + pix) = s;
}

// ---------------------------------------------------------------------------
extern "C" void kernel_launch(void* const* d_in, const int* in_sizes, int n_in,
                              void* d_out, int out_size, void* d_ws, size_t ws_size,
                              hipStream_t stream) {
  const float* x    = (const float*)d_in[0];
  const float* coef = (const float*)d_in[1];
  const float* sb   = (const float*)d_in[2];
  const float* ssp  = (const float*)d_in[3];
  const float* bias = (const float*)d_in[4];
  float* out = (float*)d_out;

  ushort_t* g    = (ushort_t*)d_ws;            // 5,326,848 B
  ushort_t* Wb   = g + G_ELEMS;                // +331,776 B
  float*    part = (float*)(Wb + WB_ELEMS);    // +4,194,304 B (16B aligned)

  hipLaunchKernelGGL(kan_feat, dim3((N_TOTAL + 255) / 256), dim3(256), 0, stream,
                     x, coef, sb, ssp, g, Wb);
  hipLaunchKernelGGL(kan_conv, dim3(512, 2), dim3(256), 0, stream, g, Wb, part);
  hipLaunchKernelGGL(kan_reduce, dim3(512), dim3(256), 0, stream, part, bias, out);
}

// Round 5
// 83.670 us; speedup vs baseline: 1.1584x; 1.1427x over previous
//
#include <hip/hip_runtime.h>

// ---------------------------------------------------------------------------
// KAN conv, fully fused (round 5):
//   out[b,o,oh,ow] = sum_{di,dj,j,c} feat_j(x[b,c,oh+di-1,ow+dj-1]) * Wb[o,pos,j,c] + bias[o]
//   feat_0 = silu(t), feat_1..8 = cubic B-spline bases (t=0 outside image —
//   basis(0) != 0, so border cells are computed, not skipped)
// kan_prep : fold Wb[o][pos][j][c] bf16 (331,776 B in d_ws)
// kan_fused: grid 512 = (b 8) x (oh 32) x (o-half 2), 512 thr = 8 waves.
//   Phase A: stage x rows -> LDS, compute 3x34-cell feature strip -> LDS bf16
//            (cell stride 592 B: 16B-aligned, bank-uniform for ds_read_b128)
//   Phase B: wave = O16 x M32 (2 acc), 4-way K-split over 81 ksteps of 32;
//            A-frags from LDS, Wb from global (L2-hot), mfma 16x16x32 bf16
//   Phase C: cross-wave reduce via dead feat LDS, + bias, direct stores.
// No g / partial global round-trips.  Workspace use: Wb only.
// ---------------------------------------------------------------------------

typedef __attribute__((ext_vector_type(8))) short v8s;
typedef __attribute__((ext_vector_type(4))) float v4f;
typedef unsigned short ushort_t;

#define WB_ELEMS    (64u * 2592u)        // 165,888 bf16
#define CELL_STRIDE 296                  // ushort elems/cell = 592 B
#define ROW_STRIDE  (34 * CELL_STRIDE)   // 10,064 elems = 20,128 B

__device__ __forceinline__ unsigned short f2bf(float v) {
  union { float f; unsigned int u; } w; w.f = v;
  unsigned int r = w.u + 0x7FFFu + ((w.u >> 16) & 1u);   // RNE
  return (unsigned short)(r >> 16);
}

// ---------------------------------------------------------------------------
// Kernel 1: fold weights  Wb[o][pos][j][c] = (j==0 ? sb : ssp*coef[j-1]), bf16
// ---------------------------------------------------------------------------
__global__ __launch_bounds__(256) void kan_prep(const float* __restrict__ coef,
                                                const float* __restrict__ sb,
                                                const float* __restrict__ ssp,
                                                ushort_t* __restrict__ Wb) {
  int i = blockIdx.x * 256 + threadIdx.x;
  if (i >= (int)WB_ELEMS) return;
  int o = i / 2592;
  int r = i - o * 2592;
  int pos = r / 288;
  int rj = r - pos * 288;
  int j = rj >> 5;
  int c = rj & 31;
  int sidx = (o * 32 + c) * 9 + pos;
  float val = (j == 0) ? sb[sidx] : ssp[sidx] * coef[sidx * 8 + (j - 1)];
  Wb[i] = f2bf(val);
}

// ---------------------------------------------------------------------------
// K-loop over flat step s = di*27 + dj*9 + kk; all offsets compile-time.
// ---------------------------------------------------------------------------
template <int LO, int HI>
__device__ __forceinline__ void kloop(const ushort_t* __restrict__ fb,
                                      const ushort_t* __restrict__ wp,
                                      v4f& acc0, v4f& acc1) {
#pragma unroll
  for (int s = LO; s < HI; ++s) {
    const int di = s / 27;
    const int dj = (s / 9) % 3;
    const int kk = s % 9;
    const int fo = di * ROW_STRIDE + dj * CELL_STRIDE + kk * 32;
    v8s wf = *(const v8s*)(wp + s * 32);
    v8s a0 = *(const v8s*)(fb + fo);
    v8s a1 = *(const v8s*)(fb + fo + 16 * CELL_STRIDE);
    acc0 = __builtin_amdgcn_mfma_f32_16x16x32_bf16(wf, a0, acc0, 0, 0, 0);
    acc1 = __builtin_amdgcn_mfma_f32_16x16x32_bf16(wf, a1, acc1, 0, 0, 0);
  }
}

// ---------------------------------------------------------------------------
// Kernel 2: fused feat + conv + reduce.
// ---------------------------------------------------------------------------
__global__ __launch_bounds__(512, 4) void kan_fused(const float* __restrict__ x,
                                                    const ushort_t* __restrict__ Wb,
                                                    const float* __restrict__ bias,
                                                    float* __restrict__ out) {
  __shared__ ushort_t feat[3 * ROW_STRIDE];   // 60,384 B
  __shared__ float xs[32 * 33];               // 4,224 B (33-word row pad)

  const int tid = threadIdx.x;
  const int bx = blockIdx.x;                  // (b*32 + oh)*2 + ohalf
  const int ohalf = bx & 1;
  const int oh = (bx >> 1) & 31;
  const int b = bx >> 6;

  // ---- Phase A: feature strip for padded rows r=0..2 (input h = oh+r-1) ----
  for (int r = 0; r < 3; ++r) {
    const int h = oh + r - 1;
    const bool hval = (h >= 0) && (h < 32);
    if (hval) {
      int idx = tid * 2;                      // 1024 floats: 32c x 32w
      int c = idx >> 5, w = idx & 31;
      float2 v = *(const float2*)(x + (((b * 32 + c) * 32 + h) * 32 + w));
      xs[c * 33 + w] = v.x;
      xs[c * 33 + w + 1] = v.y;
    }
    __syncthreads();
    for (int idx = tid; idx < 1088; idx += 512) {   // 34 cells x 32 c
      int c = idx & 31, cell = idx >> 5;
      int wi = cell - 1;
      float t = 0.0f;
      if (hval && wi >= 0 && wi < 32) t = xs[c * 33 + wi];

      unsigned short f0 = f2bf(t / (1.0f + __expf(-t)));     // silu
      float u  = (t + 2.2f) * 2.5f;                          // spline param
      float fi = floorf(u);
      int   i  = (int)fi;
      float s  = u - fi;
      float s2 = s * s, s3 = s2 * s;
      float om = 1.0f - s;
      float w0 = om * om * om * (1.0f / 6.0f);
      float w1 = (4.0f - 6.0f * s2 + 3.0f * s3) * (1.0f / 6.0f);
      float w2 = (1.0f + 3.0f * s + 3.0f * s2 - 3.0f * s3) * (1.0f / 6.0f);
      float w3 = s3 * (1.0f / 6.0f);

      ushort_t* dst = feat + r * ROW_STRIDE + cell * CELL_STRIDE + c;
      dst[0] = f0;
#pragma unroll
      for (int jj = 0; jj < 8; ++jj) {
        int d = jj - i + 3;
        float bv = (d == 0) ? w0 : (d == 1) ? w1 : (d == 2) ? w2 : (d == 3) ? w3 : 0.0f;
        dst[(jj + 1) * 32] = f2bf(bv);
      }
    }
    __syncthreads();
  }

  // ---- Phase B: MFMA.  wave = (og: O16-group) x M32, kq = K-quarter ----
  const int wv   = tid >> 6;
  const int lane = tid & 63;
  const int row  = lane & 15;
  const int quad = lane >> 4;
  const int og   = wv & 1;
  const int kq   = wv >> 1;
  const int obase = ohalf * 32 + og * 16;

  const ushort_t* fb = feat + row * CELL_STRIDE + quad * 8;
  const ushort_t* wp = Wb + (size_t)(obase + row) * 2592 + quad * 8;

  v4f acc0 = {0.f, 0.f, 0.f, 0.f};
  v4f acc1 = acc0;

  if (kq == 0)      kloop<0, 20>(fb, wp, acc0, acc1);
  else if (kq == 1) kloop<20, 40>(fb, wp, acc0, acc1);
  else if (kq == 2) kloop<40, 60>(fb, wp, acc0, acc1);
  else              kloop<60, 81>(fb, wp, acc0, acc1);

  // ---- Phase C: cross-wave reduce via dead feat LDS, + bias, store ----
  __syncthreads();
  float* red = (float*)feat;                  // 6 groups x 512 fp32 = 12 KB
  if (kq != 0) {
    float* rp = red + ((kq - 1) * 2 + og) * 512 + quad * 4 * 32 + row;
#pragma unroll
    for (int r = 0; r < 4; ++r) {
      rp[r * 32]      = acc0[r];              // pix = row      (m=0)
      rp[r * 32 + 16] = acc1[r];              // pix = 16 + row (m=1)
    }
  }
  __syncthreads();
  if (kq == 0) {
    float* o0 = out + ((size_t)(b * 64 + obase + quad * 4)) * 1024 + oh * 32 + row;
#pragma unroll
    for (int r = 0; r < 4; ++r) {
      float bv = bias[obase + quad * 4 + r];
      float s0 = acc0[r], s1 = acc1[r];
#pragma unroll
      for (int gs = 0; gs < 3; ++gs) {
        const float* rp = red + (gs * 2 + og) * 512 + (quad * 4 + r) * 32 + row;
        s0 += rp[0];
        s1 += rp[16];
      }
      o0[(size_t)r * 1024]      = s0 + bv;
      o0[(size_t)r * 1024 + 16] = s1 + bv;
    }
  }
}

// ---------------------------------------------------------------------------
extern "C" void kernel_launch(void* const* d_in, const int* in_sizes, int n_in,
                              void* d_out, int out_size, void* d_ws, size_t ws_size,
                              hipStream_t stream) {
  const float* x    = (const float*)d_in[0];
  const float* coef = (const float*)d_in[1];
  const float* sb   = (const float*)d_in[2];
  const float* ssp  = (const float*)d_in[3];
  const float* bias = (const float*)d_in[4];
  float* out = (float*)d_out;

  ushort_t* Wb = (ushort_t*)d_ws;             // 331,776 B

  hipLaunchKernelGGL(kan_prep, dim3(648), dim3(256), 0, stream, coef, sb, ssp, Wb);
  hipLaunchKernelGGL(kan_fused, dim3(512), dim3(512), 0, stream, x, Wb, bias, out);
}